// Round 4
// baseline (1170.171 us; speedup 1.0000x reference)
//
// R14: revert the R13 occupancy mistake, keep the barrier removal.
// R13 post-mortem: __launch_bounds__(256,4) capped unified VGPRs at 128;
// kernel needs ~190 (124 arch + 64 acc) -> re-spilled (VGPR=64, WRITE 308MB,
// 378us). k_gru_mfma occupancy is VGPR-bound at 2 waves/SIMD. This round:
// (256,2) + wave-private no-barrier structure = clean A/B of barrier removal
// vs R12's 313us at fixed occupancy.
#include <hip/hip_runtime.h>

#define G_KP 20
#define G_LN_EPS 1e-5f

typedef float v4f __attribute__((ext_vector_type(4)));
typedef short v8s __attribute__((ext_vector_type(8)));
typedef short v4s __attribute__((ext_vector_type(4)));

__device__ __forceinline__ unsigned short f2b(float x) {
  union { float f; unsigned int i; } c;
  c.f = x;
  return (unsigned short)((c.i + 0x7FFFu + ((c.i >> 16) & 1u)) >> 16);
}
__device__ __forceinline__ float b2f(unsigned short u) {
  union { unsigned int i; float f; } c;
  c.i = ((unsigned int)u) << 16;
  return c.f;
}

// original stub symbol (kept; harmless)
__global__ void GNNLayerKAFP_76871324663923_kernel() {}

__global__ void k_fill(float* out, int n, float v) {
  int i = blockIdx.x * 256 + threadIdx.x;
  if (i < n) out[i] = v;
}

__global__ void k_zero(float* p, int n) {
  int i = blockIdx.x * 256 + threadIdx.x;
  if (i < n) p[i] = 0.0f;
}

// ---- B-fragment packers: B[k][n] -> buf[(((kt*NT)+n0)*64+l)*8+j], bf16 ----
// k = kt*32 + (l>>4)*8 + j ; n = n0*16 + (l&15)

__global__ void k_prep_wk2b(const float* Wk2, unsigned short* Wk2b) {
  int id = blockIdx.x * 256 + threadIdx.x;
  if (id >= 13 * 8 * 64 * 8) return;
  int j = id & 7, l = (id >> 3) & 63, n0 = (id >> 9) & 7, kt = id >> 12;
  int k = kt * 32 + (l >> 4) * 8 + j;
  int n = n0 * 16 + (l & 15);
  Wk2b[id] = f2b((k < 400) ? Wk2[k * 128 + n] : 0.0f);
}

__global__ void k_prep_wpnb(const float* Wpn, unsigned short* WpnB) {
  int id = blockIdx.x * 256 + threadIdx.x;
  if (id >= 4 * 8 * 64 * 8) return;
  int j = id & 7, l = (id >> 3) & 63, n0 = (id >> 9) & 7, kt = id >> 12;
  int k = kt * 32 + (l >> 4) * 8 + j;
  int n = n0 * 16 + (l & 15);
  WpnB[id] = f2b(Wpn[k * 128 + n]);
}

// Gates: K=256 ([cx|x]), N=512 block-structured (see R9 comment)
__global__ void k_prep_wgb(const float* Wih, const float* Whh, unsigned short* WgB) {
  int id = blockIdx.x * 256 + threadIdx.x;
  if (id >= 8 * 32 * 64 * 8) return;
  int j = id & 7, l = (id >> 3) & 63, n0 = (id >> 9) & 31, kt = id >> 14;
  int k = kt * 32 + (l >> 4) * 8 + j;
  int jj = n0 * 16 + (l & 15);
  float v = 0.0f;
  if (jj < 256)      v = (k < 128) ? Wih[jj * 128 + k] : Whh[jj * 128 + (k - 128)];
  else if (jj < 384) { if (k < 128)  v = Wih[jj * 128 + k]; }
  else               { if (k >= 128) v = Whh[(jj - 128) * 128 + (k - 128)]; }
  WgB[id] = f2b(v);
}

__global__ void k_prep_wcb(const float* Wc, unsigned short* WcB) {
  int id = blockIdx.x * 256 + threadIdx.x;
  if (id >= 8 * 8 * 64 * 8) return;
  int j = id & 7, l = (id >> 3) & 63, n0 = (id >> 9) & 7, kt = id >> 12;
  int k = kt * 32 + (l >> 4) * 8 + j;
  int n = n0 * 16 + (l & 15);
  WcB[id] = f2b(Wc[k * 128 + n]);
}

// npj = relu(LN(nf @ Wk1 + bk1)) : [V,20]
__global__ void k_npj(const float* nf, const float* Wk1, const float* bk1,
                      const float* g, const float* b, float* npj) {
  int v = blockIdx.x;
  int lane = threadIdx.x;  // 64 threads
  __shared__ float x[128];
  __shared__ float y[G_KP];
  __shared__ float st[2];
  x[lane]      = nf[v * 128 + lane];
  x[lane + 64] = nf[v * 128 + 64 + lane];
  __syncthreads();
  if (lane < G_KP) {
    float acc = bk1[lane];
    for (int t = 0; t < 128; ++t) acc += x[t] * Wk1[t * G_KP + lane];
    y[lane] = acc;
  }
  __syncthreads();
  if (lane == 0) {
    float s = 0.0f, ss = 0.0f;
    for (int i = 0; i < G_KP; ++i) { s += y[i]; ss += y[i] * y[i]; }
    float mu = s * (1.0f / G_KP);
    float var = ss * (1.0f / G_KP) - mu * mu;
    st[0] = mu;
    st[1] = rsqrtf(fmaxf(var, 0.0f) + G_LN_EPS);
  }
  __syncthreads();
  if (lane < G_KP) {
    float val = (y[lane] - st[0]) * st[1] * g[lane] + b[lane];
    npj[v * G_KP + lane] = fmaxf(val, 0.0f);
  }
}

// a[e] = exp(relu(he @ We + be)); asum[dst] += a
__global__ void k_logit(const float* nf, const int* src, const int* dst,
                        const float* We, const float* be, float* a, float* asum,
                        int nE) {
  int wave = threadIdx.x >> 6, lane = threadIdx.x & 63;
  int e = blockIdx.x * 4 + wave;
  if (e >= nE) return;
  int s = src[e], d = dst[e];
  float p = nf[d * 128 + lane]      * We[lane]
          + nf[d * 128 + 64 + lane] * We[64 + lane]
          + nf[s * 128 + lane]      * We[128 + lane]
          + nf[s * 128 + 64 + lane] * We[192 + lane];
  for (int off = 32; off > 0; off >>= 1) p += __shfl_down(p, off, 64);
  if (lane == 0) {
    float lg = fmaxf(p + be[0], 0.0f);
    float av = __expf(fminf(lg, 60.0f));
    a[e] = av;
    atomicAdd(&asum[d], av);
  }
}

// wctx[dst] += (a/asum[dst]) * nf[src]   (W_pn applied after aggregation)
__global__ void k_ctx(const int* src, const int* dst, const float* a,
                      const float* asum, const float* nf, float* wctx, int nE) {
  int wave = threadIdx.x >> 6, lane = threadIdx.x & 63;
  int e = blockIdx.x * 4 + wave;
  if (e >= nE) return;
  int s = src[e], d = dst[e];
  float coef = a[e] / fmaxf(asum[d], 1e-20f);
  atomicAdd(&wctx[d * 128 + lane],      nf[s * 128 + lane] * coef);
  atomicAdd(&wctx[d * 128 + 64 + lane], nf[s * 128 + 64 + lane] * coef);
}

// kron branch MFMA: relu(LN(kron @ Wk2 + bk2)) -> atomic kf[dst]
// wave-private (16 edges per wave), zero barriers.
__global__ void __launch_bounds__(256, 2)
k_kron_mfma(const int* src, const int* dst, const float* npj,
            const unsigned short* Wk2b, const float* bk2,
            const float* g, const float* b, float* kf, int nE) {
  __shared__ unsigned short A_lds[64 * 424];
  __shared__ unsigned short sd[64][40];
  __shared__ int eidx[64][2];
  int t = threadIdx.x;
  int w = t >> 6, l = t & 63;
  int e0 = blockIdx.x * 64;
  int ebase = w * 16;  // this wave's 16 edges

  if (l < 16) {
    int e = e0 + ebase + l;
    int ec = (e < nE) ? e : (nE - 1);
    eidx[ebase + l][0] = src[ec];
    eidx[ebase + l][1] = (e < nE) ? dst[ec] : -1;
  }
  // sd: 16 edges x 40 vals = 640 per wave, 10 per lane
  #pragma unroll
  for (int k = 0; k < 10; ++k) {
    int i = l + k * 64;
    int er = i / 40, p = i - er * 40;
    int e = ebase + er;
    float v = (p < 20) ? npj[eidx[e][0] * G_KP + p]
                       : npj[((eidx[e][1] < 0) ? eidx[e][0] : eidx[e][1]) * G_KP + (p - 20)];
    sd[e][p] = f2b(v);
  }
  // zero pad cols 400..415 (16 edges x 16 = 256 per wave)
  #pragma unroll
  for (int k = 0; k < 4; ++k) {
    int i = l + k * 64;
    int e = ebase + (i >> 4), kk = 400 + (i & 15);
    A_lds[e * 424 + kk] = 0;
  }
  // kron products: 16 edges x 20 i20 = 320 tasks per wave, 5 per lane
  #pragma unroll
  for (int k = 0; k < 5; ++k) {
    int task = l + k * 64;
    int er = task / 20;
    int i20 = task - er * 20;
    int e = ebase + er;
    float s = b2f(sd[e][i20]);
    int base = e * 424 + i20 * 20;
    #pragma unroll
    for (int j20 = 0; j20 < 20; ++j20)
      A_lds[base + j20] = f2b(s * b2f(sd[e][20 + j20]));
  }

  int c15 = l & 15, quad = l >> 4;
  v4f acc[8];
  #pragma unroll
  for (int n0 = 0; n0 < 8; ++n0)
    #pragma unroll
    for (int r = 0; r < 4; ++r) acc[n0][r] = 0.0f;

  const v8s* BG = (const v8s*)Wk2b;
  int abase = (ebase + c15) * 424 + quad * 8;
  for (int kt = 0; kt < 13; ++kt) {
    v8s a = *(const v8s*)&A_lds[abase + kt * 32];
    #pragma unroll
    for (int n0 = 0; n0 < 8; ++n0) {
      v8s bb = BG[(kt * 8 + n0) * 64 + l];
      acc[n0] = __builtin_amdgcn_mfma_f32_16x16x32_bf16(a, bb, acc[n0], 0, 0, 0);
    }
  }
  float biasv[8], gv[8], bv[8];
  #pragma unroll
  for (int n0 = 0; n0 < 8; ++n0) {
    int n = n0 * 16 + c15;
    biasv[n0] = bk2[n]; gv[n0] = g[n]; bv[n0] = b[n];
  }
  float mu[4], rs[4];
  #pragma unroll
  for (int r = 0; r < 4; ++r) {
    float s = 0.0f, q = 0.0f;
    #pragma unroll
    for (int n0 = 0; n0 < 8; ++n0) {
      float v = acc[n0][r] + biasv[n0];
      s += v; q += v * v;
    }
    for (int m = 1; m < 16; m <<= 1) {
      s += __shfl_xor(s, m, 64);
      q += __shfl_xor(q, m, 64);
    }
    float mm = s * (1.0f / 128.0f);
    float vv = q * (1.0f / 128.0f) - mm * mm;
    mu[r] = mm;
    rs[r] = rsqrtf(fmaxf(vv, 0.0f) + G_LN_EPS);
  }
  #pragma unroll
  for (int r = 0; r < 4; ++r) {
    int eloc = ebase + quad * 4 + r;
    int de = eidx[eloc][1];
    if (de < 0) continue;
    #pragma unroll
    for (int n0 = 0; n0 < 8; ++n0) {
      float v = acc[n0][r] + biasv[n0];
      float y = fmaxf((v - mu[r]) * rs[r] * gv[n0] + bv[n0], 0.0f);
      atomicAdd(&kf[de * 128 + n0 * 16 + c15], y);
    }
  }
}

// GRU + final, all-MFMA, 64 nodes/block, wave-private 16-row tiles.
// (256,2): VGPR-bound occupancy — (256,4) re-spills (R13). No barriers.
__global__ void __launch_bounds__(256, 2)
k_gru_mfma(const float* nf, const float* wctx, const float* kf,
           const unsigned short* WpnB, const float* bpn,
           const unsigned short* WgB,
           const float* b_ih, const float* b_hh,
           const float* g1, const float* b1,
           const unsigned short* WcB, const float* bc,
           const float* g2, const float* b2, float* out,
           int nV) {
  __shared__ unsigned short CX[64][264];
  int t = threadIdx.x;
  int w = t >> 6, l = t & 63;
  int c15 = l & 15, quad = l >> 4;
  int v0 = blockIdx.x * 64;
  int rowbase = w * 16;

  // wave-private staging: wave w stages its own rows [16w,16w+16), float4
  #pragma unroll
  for (int k = 0; k < 8; ++k) {
    int i = l + k * 64;          // 0..511
    int r = i >> 5;              // row 0..15
    int seg = i & 31;            // float4 index 0..31
    int vn = v0 + rowbase + r; if (vn >= nV) vn = nV - 1;
    v4f wc = *(const v4f*)&wctx[vn * 128 + seg * 4];
    v4f xf = *(const v4f*)&nf[vn * 128 + seg * 4];
    v4s pw = { (short)f2b(wc[0]), (short)f2b(wc[1]), (short)f2b(wc[2]), (short)f2b(wc[3]) };
    v4s px = { (short)f2b(xf[0]), (short)f2b(xf[1]), (short)f2b(xf[2]), (short)f2b(xf[3]) };
    *(v4s*)&CX[rowbase + r][seg * 4]       = pw;
    *(v4s*)&CX[rowbase + r][128 + seg * 4] = px;
  }
  // no barriers from here on: every LDS access below is to this wave's rows

  // ---- stage 1: cx = relu(wctx @ Wpn + bpn) -> CX[:,0:128] ----
  {
    v4f acc[8];
    #pragma unroll
    for (int n0 = 0; n0 < 8; ++n0)
      #pragma unroll
      for (int r = 0; r < 4; ++r) acc[n0][r] = 0.0f;
    const v8s* BG = (const v8s*)WpnB;
    #pragma unroll
    for (int kt = 0; kt < 4; ++kt) {
      v8s a = *(const v8s*)&CX[rowbase + c15][kt * 32 + quad * 8];
      #pragma unroll
      for (int n0 = 0; n0 < 8; ++n0) {
        v8s bb = BG[(kt * 8 + n0) * 64 + l];
        acc[n0] = __builtin_amdgcn_mfma_f32_16x16x32_bf16(a, bb, acc[n0], 0, 0, 0);
      }
    }
    #pragma unroll
    for (int n0 = 0; n0 < 8; ++n0) {
      int n = n0 * 16 + c15;
      float bo = bpn[n];
      #pragma unroll
      for (int r = 0; r < 4; ++r)
        CX[rowbase + quad * 4 + r][n] = f2b(fmaxf(acc[n0][r] + bo, 0.0f));
    }
  }

  // ---- stage 2, pass 1: r,z pre-acts (N tiles 0..15) -> bf16x2 carry ----
  unsigned int rz[32];
  {
    v4f acc[16];
    #pragma unroll
    for (int n0 = 0; n0 < 16; ++n0)
      #pragma unroll
      for (int r = 0; r < 4; ++r) acc[n0][r] = 0.0f;
    const v8s* BG = (const v8s*)WgB;
    #pragma unroll
    for (int kt = 0; kt < 8; ++kt) {
      v8s a = *(const v8s*)&CX[rowbase + c15][kt * 32 + quad * 8];
      #pragma unroll
      for (int n0 = 0; n0 < 16; ++n0) {
        v8s bb = BG[(kt * 32 + n0) * 64 + l];
        acc[n0] = __builtin_amdgcn_mfma_f32_16x16x32_bf16(a, bb, acc[n0], 0, 0, 0);
      }
    }
    #pragma unroll
    for (int n0 = 0; n0 < 8; ++n0) {
      int j = n0 * 16 + c15;
      float brz = b_ih[j] + b_hh[j];
      float bzz = b_ih[128 + j] + b_hh[128 + j];
      #pragma unroll
      for (int r = 0; r < 4; ++r) {
        float rp = acc[n0][r] + brz;
        float zp = acc[8 + n0][r] + bzz;
        float rr = 1.0f / (1.0f + __expf(-fmaxf(fminf(rp, 30.0f), -30.0f)));
        float zz = 1.0f / (1.0f + __expf(-fmaxf(fminf(zp, 30.0f), -30.0f)));
        rz[r * 8 + n0] = (unsigned int)f2b(rr) | ((unsigned int)f2b(zz) << 16);
      }
    }
  }
  // ---- stage 2, pass 2: gi_n, gh_n (N tiles 16..31) + GRU + LN ----
  {
    v4f acc[16];
    #pragma unroll
    for (int n0 = 0; n0 < 16; ++n0)
      #pragma unroll
      for (int r = 0; r < 4; ++r) acc[n0][r] = 0.0f;
    const v8s* BG = (const v8s*)WgB;
    #pragma unroll
    for (int kt = 0; kt < 8; ++kt) {
      v8s a = *(const v8s*)&CX[rowbase + c15][kt * 32 + quad * 8];
      #pragma unroll
      for (int n0 = 0; n0 < 16; ++n0) {
        v8s bb = BG[(kt * 32 + 16 + n0) * 64 + l];
        acc[n0] = __builtin_amdgcn_mfma_f32_16x16x32_bf16(a, bb, acc[n0], 0, 0, 0);
      }
    }
    #pragma unroll
    for (int r = 0; r < 4; ++r) {
      int row = rowbase + quad * 4 + r;
      float h[8];
      float s = 0.0f, q = 0.0f;
      #pragma unroll
      for (int n0 = 0; n0 < 8; ++n0) {
        int j = n0 * 16 + c15;
        float gi = acc[n0][r] + b_ih[256 + j];
        float gh = acc[8 + n0][r] + b_hh[256 + j];
        unsigned int pk = rz[r * 8 + n0];
        float rr = b2f((unsigned short)(pk & 0xFFFFu));
        float zz = b2f((unsigned short)(pk >> 16));
        float an = fmaxf(fminf(gi + rr * gh, 15.0f), -15.0f);
        float e2 = __expf(-2.0f * an);
        float nn = (1.0f - e2) / (1.0f + e2);
        float x  = b2f(CX[row][128 + j]);
        float hv = fmaxf((1.0f - zz) * nn + zz * x, 0.0f);   // relu BEFORE LN
        h[n0] = hv; s += hv; q += hv * hv;
      }
      for (int m = 1; m < 16; m <<= 1) {
        s += __shfl_xor(s, m, 64);
        q += __shfl_xor(q, m, 64);
      }
      float mu = s * (1.0f / 128.0f);
      float var = q * (1.0f / 128.0f) - mu * mu;
      float rstd = rsqrtf(fmaxf(var, 0.0f) + G_LN_EPS);
      #pragma unroll
      for (int n0 = 0; n0 < 8; ++n0) {
        int j = n0 * 16 + c15;
        CX[row][j] = f2b((h[n0] - mu) * rstd * g1[j] + b1[j]);
      }
    }
  }

  // ---- stage kf into CX[:,128:256] (wave-private rows, float4) ----
  #pragma unroll
  for (int k = 0; k < 8; ++k) {
    int i = l + k * 64;
    int r = i >> 5, seg = i & 31;
    int vn = v0 + rowbase + r; if (vn >= nV) vn = nV - 1;
    v4f kv = *(const v4f*)&kf[vn * 128 + seg * 4];
    v4s pk = { (short)f2b(kv[0]), (short)f2b(kv[1]), (short)f2b(kv[2]), (short)f2b(kv[3]) };
    *(v4s*)&CX[rowbase + r][128 + seg * 4] = pk;
  }

  // ---- stage 3: out = relu(LN(cat(gru_ln, kf) @ Wc + bc)) ----
  {
    v4f acc[8];
    #pragma unroll
    for (int n0 = 0; n0 < 8; ++n0)
      #pragma unroll
      for (int r = 0; r < 4; ++r) acc[n0][r] = 0.0f;
    const v8s* BG = (const v8s*)WcB;
    #pragma unroll
    for (int kt = 0; kt < 8; ++kt) {
      v8s a = *(const v8s*)&CX[rowbase + c15][kt * 32 + quad * 8];
      #pragma unroll
      for (int n0 = 0; n0 < 8; ++n0) {
        v8s bb = BG[(kt * 8 + n0) * 64 + l];
        acc[n0] = __builtin_amdgcn_mfma_f32_16x16x32_bf16(a, bb, acc[n0], 0, 0, 0);
      }
    }
    #pragma unroll
    for (int r = 0; r < 4; ++r) {
      float vv[8];
      float s = 0.0f, q = 0.0f;
      #pragma unroll
      for (int n0 = 0; n0 < 8; ++n0) {
        vv[n0] = acc[n0][r] + bc[n0 * 16 + c15];
        s += vv[n0]; q += vv[n0] * vv[n0];
      }
      for (int m = 1; m < 16; m <<= 1) {
        s += __shfl_xor(s, m, 64);
        q += __shfl_xor(q, m, 64);
      }
      float mu = s * (1.0f / 128.0f);
      float var = q * (1.0f / 128.0f) - mu * mu;
      float rstd = rsqrtf(fmaxf(var, 0.0f) + G_LN_EPS);
      int vn = v0 + rowbase + quad * 4 + r;
      if (vn < nV) {
        #pragma unroll
        for (int n0 = 0; n0 < 8; ++n0) {
          int n = n0 * 16 + c15;
          float y = fmaxf((vv[n0] - mu) * rstd * g2[n] + b2[n], 0.0f);
          if (y != y) y = 9.0f;   // NaN canary
          out[vn * 128 + n] = y;
        }
      }
    }
  }
}

extern "C" void kernel_launch(void* const* d_in, const int* in_sizes, int n_in,
                              void* d_out, int out_size, void* d_ws, size_t ws_size,
                              hipStream_t stream) {
  (void)n_in;

  int nV = in_sizes[0] / 128;
  int nE = in_sizes[1];

  const float* nf     = (const float*)d_in[0];
  const int*   src    = (const int*)d_in[1];
  const int*   dst    = (const int*)d_in[2];
  const float* W_edge = (const float*)d_in[3];
  const float* b_edge = (const float*)d_in[4];
  const float* W_pn   = (const float*)d_in[5];
  const float* b_pn   = (const float*)d_in[6];
  const float* W_ih   = (const float*)d_in[7];
  const float* b_ih   = (const float*)d_in[8];
  const float* W_hh   = (const float*)d_in[9];
  const float* b_hh   = (const float*)d_in[10];
  const float* ln_g   = (const float*)d_in[11];
  const float* ln_b   = (const float*)d_in[12];
  const float* Wk1    = (const float*)d_in[13];
  const float* bk1    = (const float*)d_in[14];
  const float* lnk1_g = (const float*)d_in[15];
  const float* lnk1_b = (const float*)d_in[16];
  const float* Wk2    = (const float*)d_in[17];
  const float* bk2    = (const float*)d_in[18];
  const float* lnk2_g = (const float*)d_in[19];
  const float* lnk2_b = (const float*)d_in[20];
  const float* Wc     = (const float*)d_in[21];
  const float* bc     = (const float*)d_in[22];
  const float* lnc_g  = (const float*)d_in[23];
  const float* lnc_b  = (const float*)d_in[24];

  float* ws = (float*)d_ws;
  size_t off = 0;
  float* w_npj  = ws + off; off += (size_t)nV * G_KP;
  float* w_a    = ws + off; off += (size_t)nE;
  float* w_asum = ws + off; off += (size_t)nV;           // zeroed
  float* w_wctx = ws + off; off += (size_t)nV * 128;     // zeroed
  float* w_kf   = ws + off; off += (size_t)nV * 128;     // zeroed
  unsigned short* w_wk2b = (unsigned short*)(ws + off); off += 26624;
  unsigned short* w_wpnb = (unsigned short*)(ws + off); off += 8192;
  unsigned short* w_wgb  = (unsigned short*)(ws + off); off += 65536;
  unsigned short* w_wcb  = (unsigned short*)(ws + off); off += 16384;
  size_t need_bytes = off * 4;

  if (ws_size < need_bytes) {   // decodable: absmax ~= 7.0
    k_fill<<<(out_size + 255) / 256, 256, 0, stream>>>((float*)d_out, out_size, 7.0f);
    return;
  }

  // sentinel: mid-pipeline death decodes as absmax ~= 2.97
  k_fill<<<(out_size + 255) / 256, 256, 0, stream>>>((float*)d_out, out_size, 2.0f);

  int nzero = nV * 257;  // asum + wctx + kf (contiguous)
  k_zero<<<(nzero + 255) / 256, 256, 0, stream>>>(w_asum, nzero);
  k_prep_wk2b<<<208, 256, 0, stream>>>(Wk2, w_wk2b);
  k_prep_wpnb<<<64, 256, 0, stream>>>(W_pn, w_wpnb);
  k_prep_wgb<<<512, 256, 0, stream>>>(W_ih, W_hh, w_wgb);
  k_prep_wcb<<<128, 256, 0, stream>>>(Wc, w_wcb);

  k_npj<<<nV, 64, 0, stream>>>(nf, Wk1, bk1, lnk1_g, lnk1_b, w_npj);
  k_logit<<<(nE + 3) / 4, 256, 0, stream>>>(nf, src, dst, W_edge, b_edge,
                                            w_a, w_asum, nE);
  k_ctx<<<(nE + 3) / 4, 256, 0, stream>>>(src, dst, w_a, w_asum, nf, w_wctx, nE);
  k_kron_mfma<<<(nE + 63) / 64, 256, 0, stream>>>(src, dst, w_npj, w_wk2b, bk2,
                                                  lnk2_g, lnk2_b, w_kf, nE);
  k_gru_mfma<<<(nV + 63) / 64, 256, 0, stream>>>(nf, w_wctx, w_kf, w_wpnb, b_pn,
                                                 w_wgb, b_ih, b_hh, ln_g, ln_b,
                                                 w_wcb, bc, lnc_g, lnc_b,
                                                 (float*)d_out, nV);
}

// Round 6
// 881.961 us; speedup vs baseline: 1.3268x; 1.3268x over previous
//
// R16: identical to R15 (re-run — bench attempt died to MI355X container
// infra failure twice, same signature as R0/R11; kernel re-audited for
// divergent barriers / LDS aliasing hazards, none found).
//
// R15: LDS-stage the B matrices in both MFMA kernels (canonical §5 structure).
// Evidence: R12 (barriers) 313us vs R14 (no barriers) 399us, both spill-free ->
// lockstep helped via L1 B-sharing; per-wave redundant global B-streams
// (~350 loads/wave, ~500cyc exposed each) are the stall. Fix: per-kt
// cooperative global->LDS staging of the 8-16KB B slab + prefetch, MFMA reads
// B from LDS. Kron: A stride 424->416, sd aliased with B_lds (<=64KB LDS).
#include <hip/hip_runtime.h>

#define G_KP 20
#define G_LN_EPS 1e-5f

typedef float v4f __attribute__((ext_vector_type(4)));
typedef short v8s __attribute__((ext_vector_type(8)));
typedef short v4s __attribute__((ext_vector_type(4)));

__device__ __forceinline__ unsigned short f2b(float x) {
  union { float f; unsigned int i; } c;
  c.f = x;
  return (unsigned short)((c.i + 0x7FFFu + ((c.i >> 16) & 1u)) >> 16);
}
__device__ __forceinline__ float b2f(unsigned short u) {
  union { unsigned int i; float f; } c;
  c.i = ((unsigned int)u) << 16;
  return c.f;
}

// Shared-B MFMA stage: per kt, 256 threads cooperatively stage the NT-tile
// B slab (NT KB) into LDS, barrier, then each wave MFMAs its own A rows
// against the shared slab. Next kt's slab is prefetched into regs before the
// visibility barrier so the global latency overlaps write+barrier+MFMA.
template<int NKT, int NT>
__device__ __forceinline__ void stage_mfma(
    const v8s* __restrict__ Bsrc,  // global base at kt=0 (v8s units)
    int kt_tiles,                  // tiles per kt step in source layout
    v8s* B_lds,                    // 64*NT v8s shared slab
    const unsigned short* Arow,    // per-lane A row base (LDS)
    int a_kt,                      // shorts per kt step in A row
    int a_off,                     // quad*8
    int t, int l, v4f* acc) {
  constexpr int NPR = NT / 4;      // 16B units per thread per kt
  v8s pr[NPR];
  #pragma unroll
  for (int i = 0; i < NPR; ++i) pr[i] = Bsrc[t + i * 256];
  #pragma unroll
  for (int kt = 0; kt < NKT; ++kt) {
    __syncthreads();               // WAR: all waves done reading old slab
    #pragma unroll
    for (int i = 0; i < NPR; ++i) B_lds[t + i * 256] = pr[i];
    if (kt + 1 < NKT) {
      #pragma unroll
      for (int i = 0; i < NPR; ++i)
        pr[i] = Bsrc[(kt + 1) * kt_tiles * 64 + t + i * 256];
    }
    __syncthreads();               // slab visible to all waves
    v8s a = *(const v8s*)&Arow[kt * a_kt + a_off];
    #pragma unroll
    for (int n0 = 0; n0 < NT; ++n0)
      acc[n0] = __builtin_amdgcn_mfma_f32_16x16x32_bf16(a, B_lds[n0 * 64 + l], acc[n0], 0, 0, 0);
  }
}

// original stub symbol (kept; harmless)
__global__ void GNNLayerKAFP_76871324663923_kernel() {}

__global__ void k_fill(float* out, int n, float v) {
  int i = blockIdx.x * 256 + threadIdx.x;
  if (i < n) out[i] = v;
}

__global__ void k_zero(float* p, int n) {
  int i = blockIdx.x * 256 + threadIdx.x;
  if (i < n) p[i] = 0.0f;
}

// ---- B-fragment packers: B[k][n] -> buf[(((kt*NT)+n0)*64+l)*8+j], bf16 ----
// k = kt*32 + (l>>4)*8 + j ; n = n0*16 + (l&15)

__global__ void k_prep_wk2b(const float* Wk2, unsigned short* Wk2b) {
  int id = blockIdx.x * 256 + threadIdx.x;
  if (id >= 13 * 8 * 64 * 8) return;
  int j = id & 7, l = (id >> 3) & 63, n0 = (id >> 9) & 7, kt = id >> 12;
  int k = kt * 32 + (l >> 4) * 8 + j;
  int n = n0 * 16 + (l & 15);
  Wk2b[id] = f2b((k < 400) ? Wk2[k * 128 + n] : 0.0f);
}

__global__ void k_prep_wpnb(const float* Wpn, unsigned short* WpnB) {
  int id = blockIdx.x * 256 + threadIdx.x;
  if (id >= 4 * 8 * 64 * 8) return;
  int j = id & 7, l = (id >> 3) & 63, n0 = (id >> 9) & 7, kt = id >> 12;
  int k = kt * 32 + (l >> 4) * 8 + j;
  int n = n0 * 16 + (l & 15);
  WpnB[id] = f2b(Wpn[k * 128 + n]);
}

// Gates: K=256 ([cx|x]), N=512 block-structured (see R9 comment)
__global__ void k_prep_wgb(const float* Wih, const float* Whh, unsigned short* WgB) {
  int id = blockIdx.x * 256 + threadIdx.x;
  if (id >= 8 * 32 * 64 * 8) return;
  int j = id & 7, l = (id >> 3) & 63, n0 = (id >> 9) & 31, kt = id >> 14;
  int k = kt * 32 + (l >> 4) * 8 + j;
  int jj = n0 * 16 + (l & 15);
  float v = 0.0f;
  if (jj < 256)      v = (k < 128) ? Wih[jj * 128 + k] : Whh[jj * 128 + (k - 128)];
  else if (jj < 384) { if (k < 128)  v = Wih[jj * 128 + k]; }
  else               { if (k >= 128) v = Whh[(jj - 128) * 128 + (k - 128)]; }
  WgB[id] = f2b(v);
}

__global__ void k_prep_wcb(const float* Wc, unsigned short* WcB) {
  int id = blockIdx.x * 256 + threadIdx.x;
  if (id >= 8 * 8 * 64 * 8) return;
  int j = id & 7, l = (id >> 3) & 63, n0 = (id >> 9) & 7, kt = id >> 12;
  int k = kt * 32 + (l >> 4) * 8 + j;
  int n = n0 * 16 + (l & 15);
  WcB[id] = f2b(Wc[k * 128 + n]);
}

// npj = relu(LN(nf @ Wk1 + bk1)) : [V,20]
__global__ void k_npj(const float* nf, const float* Wk1, const float* bk1,
                      const float* g, const float* b, float* npj) {
  int v = blockIdx.x;
  int lane = threadIdx.x;  // 64 threads
  __shared__ float x[128];
  __shared__ float y[G_KP];
  __shared__ float st[2];
  x[lane]      = nf[v * 128 + lane];
  x[lane + 64] = nf[v * 128 + 64 + lane];
  __syncthreads();
  if (lane < G_KP) {
    float acc = bk1[lane];
    for (int t = 0; t < 128; ++t) acc += x[t] * Wk1[t * G_KP + lane];
    y[lane] = acc;
  }
  __syncthreads();
  if (lane == 0) {
    float s = 0.0f, ss = 0.0f;
    for (int i = 0; i < G_KP; ++i) { s += y[i]; ss += y[i] * y[i]; }
    float mu = s * (1.0f / G_KP);
    float var = ss * (1.0f / G_KP) - mu * mu;
    st[0] = mu;
    st[1] = rsqrtf(fmaxf(var, 0.0f) + G_LN_EPS);
  }
  __syncthreads();
  if (lane < G_KP) {
    float val = (y[lane] - st[0]) * st[1] * g[lane] + b[lane];
    npj[v * G_KP + lane] = fmaxf(val, 0.0f);
  }
}

// a[e] = exp(relu(he @ We + be)); asum[dst] += a
__global__ void k_logit(const float* nf, const int* src, const int* dst,
                        const float* We, const float* be, float* a, float* asum,
                        int nE) {
  int wave = threadIdx.x >> 6, lane = threadIdx.x & 63;
  int e = blockIdx.x * 4 + wave;
  if (e >= nE) return;
  int s = src[e], d = dst[e];
  float p = nf[d * 128 + lane]      * We[lane]
          + nf[d * 128 + 64 + lane] * We[64 + lane]
          + nf[s * 128 + lane]      * We[128 + lane]
          + nf[s * 128 + 64 + lane] * We[192 + lane];
  for (int off = 32; off > 0; off >>= 1) p += __shfl_down(p, off, 64);
  if (lane == 0) {
    float lg = fmaxf(p + be[0], 0.0f);
    float av = __expf(fminf(lg, 60.0f));
    a[e] = av;
    atomicAdd(&asum[d], av);
  }
}

// wctx[dst] += (a/asum[dst]) * nf[src]   (W_pn applied after aggregation)
__global__ void k_ctx(const int* src, const int* dst, const float* a,
                      const float* asum, const float* nf, float* wctx, int nE) {
  int wave = threadIdx.x >> 6, lane = threadIdx.x & 63;
  int e = blockIdx.x * 4 + wave;
  if (e >= nE) return;
  int s = src[e], d = dst[e];
  float coef = a[e] / fmaxf(asum[d], 1e-20f);
  atomicAdd(&wctx[d * 128 + lane],      nf[s * 128 + lane] * coef);
  atomicAdd(&wctx[d * 128 + 64 + lane], nf[s * 128 + 64 + lane] * coef);
}

// kron branch MFMA: relu(LN(kron @ Wk2 + bk2)) -> atomic kf[dst]
// Wave-private A-build (16 edges/wave); B staged via LDS per kt.
// LDS: A 64*416*2=53248 + eidx 512 + SDB 8192 (sd during build, B_lds after)
// = 61952B <= 64KB.
__global__ void __launch_bounds__(256, 2)
k_kron_mfma(const int* src, const int* dst, const float* npj,
            const unsigned short* Wk2b, const float* bk2,
            const float* g, const float* b, float* kf, int nE) {
  __shared__ unsigned short A_lds[64 * 416];
  __shared__ int eidx[64][2];
  __shared__ unsigned short SDB[4096];   // sd[64][40] during build; B slab later
  unsigned short (*sd)[40] = (unsigned short(*)[40])SDB;
  v8s* B_lds = (v8s*)SDB;

  int t = threadIdx.x;
  int w = t >> 6, l = t & 63;
  int e0 = blockIdx.x * 64;
  int ebase = w * 16;  // this wave's 16 edges

  if (l < 16) {
    int e = e0 + ebase + l;
    int ec = (e < nE) ? e : (nE - 1);
    eidx[ebase + l][0] = src[ec];
    eidx[ebase + l][1] = (e < nE) ? dst[ec] : -1;
  }
  // sd: 16 edges x 40 vals = 640 per wave, 10 per lane
  #pragma unroll
  for (int k = 0; k < 10; ++k) {
    int i = l + k * 64;
    int er = i / 40, p = i - er * 40;
    int e = ebase + er;
    float v = (p < 20) ? npj[eidx[e][0] * G_KP + p]
                       : npj[((eidx[e][1] < 0) ? eidx[e][0] : eidx[e][1]) * G_KP + (p - 20)];
    sd[e][p] = f2b(v);
  }
  // zero pad cols 400..415 (16 edges x 16 = 256 per wave)
  #pragma unroll
  for (int k = 0; k < 4; ++k) {
    int i = l + k * 64;
    int e = ebase + (i >> 4), kk = 400 + (i & 15);
    A_lds[e * 416 + kk] = 0;
  }
  // kron products: 16 edges x 20 i20 = 320 tasks per wave, 5 per lane
  #pragma unroll
  for (int k = 0; k < 5; ++k) {
    int task = l + k * 64;
    int er = task / 20;
    int i20 = task - er * 20;
    int e = ebase + er;
    float s = b2f(sd[e][i20]);
    int base = e * 416 + i20 * 20;
    #pragma unroll
    for (int j20 = 0; j20 < 20; ++j20)
      A_lds[base + j20] = f2b(s * b2f(sd[e][20 + j20]));
  }
  // stage_mfma's first __syncthreads guarantees all waves finished the sd
  // reads above before B staging overwrites SDB.

  int c15 = l & 15, quad = l >> 4;
  v4f acc[8];
  #pragma unroll
  for (int n0 = 0; n0 < 8; ++n0)
    #pragma unroll
    for (int r = 0; r < 4; ++r) acc[n0][r] = 0.0f;

  stage_mfma<13, 8>((const v8s*)Wk2b, 8, B_lds,
                    &A_lds[(ebase + c15) * 416], 32, quad * 8, t, l, acc);

  float biasv[8], gv[8], bv[8];
  #pragma unroll
  for (int n0 = 0; n0 < 8; ++n0) {
    int n = n0 * 16 + c15;
    biasv[n0] = bk2[n]; gv[n0] = g[n]; bv[n0] = b[n];
  }
  float mu[4], rs[4];
  #pragma unroll
  for (int r = 0; r < 4; ++r) {
    float s = 0.0f, q = 0.0f;
    #pragma unroll
    for (int n0 = 0; n0 < 8; ++n0) {
      float v = acc[n0][r] + biasv[n0];
      s += v; q += v * v;
    }
    for (int m = 1; m < 16; m <<= 1) {
      s += __shfl_xor(s, m, 64);
      q += __shfl_xor(q, m, 64);
    }
    float mm = s * (1.0f / 128.0f);
    float vv = q * (1.0f / 128.0f) - mm * mm;
    mu[r] = mm;
    rs[r] = rsqrtf(fmaxf(vv, 0.0f) + G_LN_EPS);
  }
  #pragma unroll
  for (int r = 0; r < 4; ++r) {
    int eloc = ebase + quad * 4 + r;
    int de = eidx[eloc][1];
    if (de < 0) continue;
    #pragma unroll
    for (int n0 = 0; n0 < 8; ++n0) {
      float v = acc[n0][r] + biasv[n0];
      float y = fmaxf((v - mu[r]) * rs[r] * gv[n0] + bv[n0], 0.0f);
      atomicAdd(&kf[de * 128 + n0 * 16 + c15], y);
    }
  }
}

// GRU + final, all-MFMA, 64 nodes/block, wave-private 16-row A tiles,
// B staged via LDS per kt (shared by the 4 waves).
__global__ void __launch_bounds__(256, 2)
k_gru_mfma(const float* nf, const float* wctx, const float* kf,
           const unsigned short* WpnB, const float* bpn,
           const unsigned short* WgB,
           const float* b_ih, const float* b_hh,
           const float* g1, const float* b1,
           const unsigned short* WcB, const float* bc,
           const float* g2, const float* b2, float* out,
           int nV) {
  __shared__ unsigned short CX[64][264];
  __shared__ v8s B_lds[1024];    // 16KB slab (NT up to 16)
  int t = threadIdx.x;
  int w = t >> 6, l = t & 63;
  int c15 = l & 15, quad = l >> 4;
  int v0 = blockIdx.x * 64;
  int rowbase = w * 16;

  // wave-private staging: wave w stages its own rows [16w,16w+16), float4
  #pragma unroll
  for (int k = 0; k < 8; ++k) {
    int i = l + k * 64;          // 0..511
    int r = i >> 5;              // row 0..15
    int seg = i & 31;            // float4 index 0..31
    int vn = v0 + rowbase + r; if (vn >= nV) vn = nV - 1;
    v4f wc = *(const v4f*)&wctx[vn * 128 + seg * 4];
    v4f xf = *(const v4f*)&nf[vn * 128 + seg * 4];
    v4s pw = { (short)f2b(wc[0]), (short)f2b(wc[1]), (short)f2b(wc[2]), (short)f2b(wc[3]) };
    v4s px = { (short)f2b(xf[0]), (short)f2b(xf[1]), (short)f2b(xf[2]), (short)f2b(xf[3]) };
    *(v4s*)&CX[rowbase + r][seg * 4]       = pw;
    *(v4s*)&CX[rowbase + r][128 + seg * 4] = px;
  }
  // (CX rows are wave-private; barriers below only protect B_lds)

  // ---- stage 1: cx = relu(wctx @ Wpn + bpn) -> CX[:,0:128] ----
  {
    v4f acc[8];
    #pragma unroll
    for (int n0 = 0; n0 < 8; ++n0)
      #pragma unroll
      for (int r = 0; r < 4; ++r) acc[n0][r] = 0.0f;
    stage_mfma<4, 8>((const v8s*)WpnB, 8, B_lds,
                     &CX[rowbase + c15][0], 32, quad * 8, t, l, acc);
    #pragma unroll
    for (int n0 = 0; n0 < 8; ++n0) {
      int n = n0 * 16 + c15;
      float bo = bpn[n];
      #pragma unroll
      for (int r = 0; r < 4; ++r)
        CX[rowbase + quad * 4 + r][n] = f2b(fmaxf(acc[n0][r] + bo, 0.0f));
    }
  }

  // ---- stage 2, pass 1: r,z pre-acts (N tiles 0..15) -> bf16x2 carry ----
  unsigned int rz[32];
  {
    v4f acc[16];
    #pragma unroll
    for (int n0 = 0; n0 < 16; ++n0)
      #pragma unroll
      for (int r = 0; r < 4; ++r) acc[n0][r] = 0.0f;
    stage_mfma<8, 16>((const v8s*)WgB, 32, B_lds,
                      &CX[rowbase + c15][0], 32, quad * 8, t, l, acc);
    #pragma unroll
    for (int n0 = 0; n0 < 8; ++n0) {
      int j = n0 * 16 + c15;
      float brz = b_ih[j] + b_hh[j];
      float bzz = b_ih[128 + j] + b_hh[128 + j];
      #pragma unroll
      for (int r = 0; r < 4; ++r) {
        float rp = acc[n0][r] + brz;
        float zp = acc[8 + n0][r] + bzz;
        float rr = 1.0f / (1.0f + __expf(-fmaxf(fminf(rp, 30.0f), -30.0f)));
        float zz = 1.0f / (1.0f + __expf(-fmaxf(fminf(zp, 30.0f), -30.0f)));
        rz[r * 8 + n0] = (unsigned int)f2b(rr) | ((unsigned int)f2b(zz) << 16);
      }
    }
  }
  // ---- stage 2, pass 2: gi_n, gh_n (N tiles 16..31) + GRU + LN ----
  {
    v4f acc[16];
    #pragma unroll
    for (int n0 = 0; n0 < 16; ++n0)
      #pragma unroll
      for (int r = 0; r < 4; ++r) acc[n0][r] = 0.0f;
    stage_mfma<8, 16>((const v8s*)WgB + 16 * 64, 32, B_lds,
                      &CX[rowbase + c15][0], 32, quad * 8, t, l, acc);
    #pragma unroll
    for (int r = 0; r < 4; ++r) {
      int row = rowbase + quad * 4 + r;
      float h[8];
      float s = 0.0f, q = 0.0f;
      #pragma unroll
      for (int n0 = 0; n0 < 8; ++n0) {
        int j = n0 * 16 + c15;
        float gi = acc[n0][r] + b_ih[256 + j];
        float gh = acc[8 + n0][r] + b_hh[256 + j];
        unsigned int pk = rz[r * 8 + n0];
        float rr = b2f((unsigned short)(pk & 0xFFFFu));
        float zz = b2f((unsigned short)(pk >> 16));
        float an = fmaxf(fminf(gi + rr * gh, 15.0f), -15.0f);
        float e2 = __expf(-2.0f * an);
        float nn = (1.0f - e2) / (1.0f + e2);
        float x  = b2f(CX[row][128 + j]);
        float hv = fmaxf((1.0f - zz) * nn + zz * x, 0.0f);   // relu BEFORE LN
        h[n0] = hv; s += hv; q += hv * hv;
      }
      for (int m = 1; m < 16; m <<= 1) {
        s += __shfl_xor(s, m, 64);
        q += __shfl_xor(q, m, 64);
      }
      float mu = s * (1.0f / 128.0f);
      float var = q * (1.0f / 128.0f) - mu * mu;
      float rstd = rsqrtf(fmaxf(var, 0.0f) + G_LN_EPS);
      #pragma unroll
      for (int n0 = 0; n0 < 8; ++n0) {
        int j = n0 * 16 + c15;
        CX[row][j] = f2b((h[n0] - mu) * rstd * g1[j] + b1[j]);
      }
    }
  }

  // ---- stage kf into CX[:,128:256] (wave-private rows, float4) ----
  #pragma unroll
  for (int k = 0; k < 8; ++k) {
    int i = l + k * 64;
    int r = i >> 5, seg = i & 31;
    int vn = v0 + rowbase + r; if (vn >= nV) vn = nV - 1;
    v4f kv = *(const v4f*)&kf[vn * 128 + seg * 4];
    v4s pk = { (short)f2b(kv[0]), (short)f2b(kv[1]), (short)f2b(kv[2]), (short)f2b(kv[3]) };
    *(v4s*)&CX[rowbase + r][128 + seg * 4] = pk;
  }

  // ---- stage 3: out = relu(LN(cat(gru_ln, kf) @ Wc + bc)) ----
  {
    v4f acc[8];
    #pragma unroll
    for (int n0 = 0; n0 < 8; ++n0)
      #pragma unroll
      for (int r = 0; r < 4; ++r) acc[n0][r] = 0.0f;
    stage_mfma<8, 8>((const v8s*)WcB, 8, B_lds,
                     &CX[rowbase + c15][0], 32, quad * 8, t, l, acc);
    #pragma unroll
    for (int r = 0; r < 4; ++r) {
      float vv[8];
      float s = 0.0f, q = 0.0f;
      #pragma unroll
      for (int n0 = 0; n0 < 8; ++n0) {
        vv[n0] = acc[n0][r] + bc[n0 * 16 + c15];
        s += vv[n0]; q += vv[n0] * vv[n0];
      }
      for (int m = 1; m < 16; m <<= 1) {
        s += __shfl_xor(s, m, 64);
        q += __shfl_xor(q, m, 64);
      }
      float mu = s * (1.0f / 128.0f);
      float var = q * (1.0f / 128.0f) - mu * mu;
      float rstd = rsqrtf(fmaxf(var, 0.0f) + G_LN_EPS);
      int vn = v0 + rowbase + quad * 4 + r;
      if (vn < nV) {
        #pragma unroll
        for (int n0 = 0; n0 < 8; ++n0) {
          int n = n0 * 16 + c15;
          float y = fmaxf((vv[n0] - mu) * rstd * g2[n] + b2[n], 0.0f);
          if (y != y) y = 9.0f;   // NaN canary
          out[vn * 128 + n] = y;
        }
      }
    }
  }
}

extern "C" void kernel_launch(void* const* d_in, const int* in_sizes, int n_in,
                              void* d_out, int out_size, void* d_ws, size_t ws_size,
                              hipStream_t stream) {
  (void)n_in;

  int nV = in_sizes[0] / 128;
  int nE = in_sizes[1];

  const float* nf     = (const float*)d_in[0];
  const int*   src    = (const int*)d_in[1];
  const int*   dst    = (const int*)d_in[2];
  const float* W_edge = (const float*)d_in[3];
  const float* b_edge = (const float*)d_in[4];
  const float* W_pn   = (const float*)d_in[5];
  const float* b_pn   = (const float*)d_in[6];
  const float* W_ih   = (const float*)d_in[7];
  const float* b_ih   = (const float*)d_in[8];
  const float* W_hh   = (const float*)d_in[9];
  const float* b_hh   = (const float*)d_in[10];
  const float* ln_g   = (const float*)d_in[11];
  const float* ln_b   = (const float*)d_in[12];
  const float* Wk1    = (const float*)d_in[13];
  const float* bk1    = (const float*)d_in[14];
  const float* lnk1_g = (const float*)d_in[15];
  const float* lnk1_b = (const float*)d_in[16];
  const float* Wk2    = (const float*)d_in[17];
  const float* bk2    = (const float*)d_in[18];
  const float* lnk2_g = (const float*)d_in[19];
  const float* lnk2_b = (const float*)d_in[20];
  const float* Wc     = (const float*)d_in[21];
  const float* bc     = (const float*)d_in[22];
  const float* lnc_g  = (const float*)d_in[23];
  const float* lnc_b  = (const float*)d_in[24];

  float* ws = (float*)d_ws;
  size_t off = 0;
  float* w_npj  = ws + off; off += (size_t)nV * G_KP;
  float* w_a    = ws + off; off += (size_t)nE;
  float* w_asum = ws + off; off += (size_t)nV;           // zeroed
  float* w_wctx = ws + off; off += (size_t)nV * 128;     // zeroed
  float* w_kf   = ws + off; off += (size_t)nV * 128;     // zeroed
  unsigned short* w_wk2b = (unsigned short*)(ws + off); off += 26624;
  unsigned short* w_wpnb = (unsigned short*)(ws + off); off += 8192;
  unsigned short* w_wgb  = (unsigned short*)(ws + off); off += 65536;
  unsigned short* w_wcb  = (unsigned short*)(ws + off); off += 16384;
  size_t need_bytes = off * 4;

  if (ws_size < need_bytes) {   // decodable: absmax ~= 7.0
    k_fill<<<(out_size + 255) / 256, 256, 0, stream>>>((float*)d_out, out_size, 7.0f);
    return;
  }

  // sentinel: mid-pipeline death decodes as absmax ~= 2.97
  k_fill<<<(out_size + 255) / 256, 256, 0, stream>>>((float*)d_out, out_size, 2.0f);

  int nzero = nV * 257;  // asum + wctx + kf (contiguous)
  k_zero<<<(nzero + 255) / 256, 256, 0, stream>>>(w_asum, nzero);
  k_prep_wk2b<<<208, 256, 0, stream>>>(Wk2, w_wk2b);
  k_prep_wpnb<<<64, 256, 0, stream>>>(W_pn, w_wpnb);
  k_prep_wgb<<<512, 256, 0, stream>>>(W_ih, W_hh, w_wgb);
  k_prep_wcb<<<128, 256, 0, stream>>>(Wc, w_wcb);

  k_npj<<<nV, 64, 0, stream>>>(nf, Wk1, bk1, lnk1_g, lnk1_b, w_npj);
  k_logit<<<(nE + 3) / 4, 256, 0, stream>>>(nf, src, dst, W_edge, b_edge,
                                            w_a, w_asum, nE);
  k_ctx<<<(nE + 3) / 4, 256, 0, stream>>>(src, dst, w_a, w_asum, nf, w_wctx, nE);
  k_kron_mfma<<<(nE + 63) / 64, 256, 0, stream>>>(src, dst, w_npj, w_wk2b, bk2,
                                                  lnk2_g, lnk2_b, w_kf, nE);
  k_gru_mfma<<<(nV + 63) / 64, 256, 0, stream>>>(nf, w_wctx, w_kf, w_wpnb, b_pn,
                                                 w_wgb, b_ih, b_hh, ln_g, ln_b,
                                                 w_wcb, bc, lnc_g, lnc_b,
                                                 (float*)d_out, nV);
}